// Round 2
// baseline (521.920 us; speedup 1.0000x reference)
//
#include <hip/hip_runtime.h>
#include <hip/hip_bf16.h>
#include <cstdint>

#define DEVINL __device__ __forceinline__

typedef __attribute__((ext_vector_type(8))) short bf16x8;
typedef __attribute__((ext_vector_type(4))) float f32x4;

DEVINL unsigned short f2bf(float f) {
    union { float f; unsigned u; } v; v.f = f;
    unsigned r = v.u + 0x7fffu + ((v.u >> 16) & 1u);   // RNE
    return (unsigned short)(r >> 16);
}
DEVINL float bf2f(unsigned short h) {
    union { unsigned u; float f; } v; v.u = ((unsigned)h) << 16;
    return v.f;
}

constexpr int BN = 128, BK = 32;
constexpr int PITCH = 40;   // bf16 elems per LDS row = 80B (16B aligned, 2-way-free on b128 reads)
constexpr int NSP = 256;    // H*W

// ---------------------------------------------------------------------------
// Transpose + bf16 convert: x[b][K=2048][256] f32 -> xT[b][256][2048] bf16.
// Padded 64x65 f32 LDS tile; both LDS phases verified exactly 2 lanes/bank (free).
__global__ __launch_bounds__(256)
void xpose(const float* __restrict__ x, unsigned short* __restrict__ xT)
{
    __shared__ float sh[64][65];
    const int b   = blockIdx.y;
    const int kt  = blockIdx.x & 31;     // 2048/64
    const int ntb = blockIdx.x >> 5;     // 256/64
    const int k0 = kt * 64, n0 = ntb * 64;

    const int r = threadIdx.x >> 4;          // 0..15
    const int c = (threadIdx.x & 15) * 4;    // 0..60

    const float* xb = x + ((size_t)b * 2048 + k0) * 256 + n0;
#pragma unroll
    for (int i = 0; i < 4; ++i) {
        float4 v = *(const float4*)(xb + (size_t)(r + 16 * i) * 256 + c);
        sh[r + 16 * i][c + 0] = v.x;
        sh[r + 16 * i][c + 1] = v.y;
        sh[r + 16 * i][c + 2] = v.z;
        sh[r + 16 * i][c + 3] = v.w;
    }
    __syncthreads();
#pragma unroll
    for (int i = 0; i < 4; ++i) {
        const int rr = r + 16 * i;           // n within tile
        ushort4 o;
        o.x = f2bf(sh[c + 0][rr]);
        o.y = f2bf(sh[c + 1][rr]);
        o.z = f2bf(sh[c + 2][rr]);
        o.w = f2bf(sh[c + 3][rr]);
        *(ushort4*)(xT + ((size_t)b * NSP + n0 + rr) * 2048 + k0 + c) = o;
    }
}

// ---------------------------------------------------------------------------
// Y^T[b][n][m] = sigmoid( sum_k W[b][m][k] * X[..] + bias[b][m] ), bf16 out.
// A = W tile [BM][BK] K-contig; B = X^T tile [BN][BK] K-contig.
// BM=128: 2x2 waves (64x64 each, acc 4x4). BM=64: 1x4 waves (64x32, acc 4x2).
// BF32: X is fp32 [b][K][256] (fallback fused-transpose path); else bf16 [b][256][K].
template<int BM, bool BF32>
__global__ __launch_bounds__(256, 2)
void fc_gemm(const float* __restrict__ Wt, const float* __restrict__ bias,
             const void* __restrict__ Xv, unsigned short* __restrict__ Yt,
             int M, int K)
{
    constexpr int WAVES_M = BM / 64;          // 2 or 1
    constexpr int WAVES_N = 4 / WAVES_M;      // 2 or 4
    constexpr int WTN     = BN / WAVES_N;     // 64 or 32
    constexpr int AN      = WTN / 16;         // 4 or 2
    constexpr int AI      = BM / 32;          // A staging iters (4 or 2)

    const int y  = blockIdx.y;                // b + 64*nt  (nt pair ids differ by MT*64 ≡ 0 mod 8 → same XCD)
    const int b  = y & 63;
    const int nt = y >> 6;
    const int m0 = blockIdx.x * BM;
    const int n0 = nt * BN;

    __shared__ __align__(16) unsigned short sA[2][BM * PITCH];
    __shared__ __align__(16) unsigned short sB[2][BN * PITCH];

    const int tid  = threadIdx.x;
    const int lane = tid & 63;
    const int wid  = tid >> 6;
    const int wm   = (wid / WAVES_N) * 64;
    const int wn   = (wid % WAVES_N) * WTN;
    const int fr   = lane & 15;
    const int fo   = (lane >> 4) * 8;

    // A staging: BM x 32 fp32 -> bf16, float4 along K
    const int ar = tid >> 3;             // 0..31
    const int ac = (tid & 7) * 4;        // 0..28
    const float* Wb = Wt + (size_t)b * M * K + (size_t)m0 * K;

    const float*          Xf = (const float*)Xv;          // [K][256] (fallback)
    const unsigned short* Xh = (const unsigned short*)Xv; // [256][K]
    const int brow = tid >> 2, bcol = (tid & 3) * 8;
    const int bk = tid >> 5,  bn = (tid & 31) * 4;

    float4 aR[AI];
    float4 bRn[4];
    uint4  bRc[2];

    auto loadA = [&](int k0) {
#pragma unroll
        for (int i = 0; i < AI; ++i)
            aR[i] = *(const float4*)(Wb + (size_t)(ar + 32*i) * K + k0 + ac);
    };
    auto loadB = [&](int k0) {
        if constexpr (BF32) {
#pragma unroll
            for (int i = 0; i < 4; ++i)
                bRn[i] = *(const float4*)(Xf + (size_t)b*K*NSP + (size_t)(k0 + bk + 8*i)*NSP + n0 + bn);
        } else {
#pragma unroll
            for (int i = 0; i < 2; ++i)
                bRc[i] = *(const uint4*)(Xh + ((size_t)b*NSP + n0 + brow + 64*i)*K + k0 + bcol);
        }
    };
    auto storeA = [&](int buf) {
#pragma unroll
        for (int i = 0; i < AI; ++i) {
            ushort4 p;
            p.x = f2bf(aR[i].x); p.y = f2bf(aR[i].y);
            p.z = f2bf(aR[i].z); p.w = f2bf(aR[i].w);
            *(ushort4*)&sA[buf][(ar + 32*i) * PITCH + ac] = p;
        }
    };
    auto storeB = [&](int buf) {
        if constexpr (BF32) {
#pragma unroll
            for (int i = 0; i < 4; ++i) {
                const int kk = bk + 8*i;
                sB[buf][(bn+0)*PITCH + kk] = f2bf(bRn[i].x);
                sB[buf][(bn+1)*PITCH + kk] = f2bf(bRn[i].y);
                sB[buf][(bn+2)*PITCH + kk] = f2bf(bRn[i].z);
                sB[buf][(bn+3)*PITCH + kk] = f2bf(bRn[i].w);
            }
        } else {
#pragma unroll
            for (int i = 0; i < 2; ++i)
                *(uint4*)&sB[buf][(brow + 64*i) * PITCH + bcol] = bRc[i];
        }
    };

    f32x4 acc[4][AN] = {};

    loadA(0); loadB(0);
    storeA(0); storeB(0);
    __syncthreads();

    const int NT = K / BK;
    int cur = 0;
#pragma unroll 1
    for (int t = 0; t < NT; ++t) {
        if (t + 1 < NT) { loadA((t+1)*BK); loadB((t+1)*BK); }  // in flight under MFMA

        bf16x8 af[4], bfr[AN];
#pragma unroll
        for (int i = 0; i < 4; ++i)
            af[i] = *(const bf16x8*)&sA[cur][(wm + i*16 + fr) * PITCH + fo];
#pragma unroll
        for (int i = 0; i < AN; ++i)
            bfr[i] = *(const bf16x8*)&sB[cur][(wn + i*16 + fr) * PITCH + fo];
#pragma unroll
        for (int mi = 0; mi < 4; ++mi)
#pragma unroll
            for (int ni = 0; ni < AN; ++ni)
                acc[mi][ni] = __builtin_amdgcn_mfma_f32_16x16x32_bf16(af[mi], bfr[ni], acc[mi][ni], 0, 0, 0);

        if (t + 1 < NT) { storeA(cur ^ 1); storeB(cur ^ 1); }
        __syncthreads();
        cur ^= 1;
    }

    // Epilogue: D col = lane&15 (n), rows = (lane>>4)*4+q (m). Store Y^T[b][n][m] bf16.
#pragma unroll
    for (int mi = 0; mi < 4; ++mi) {
#pragma unroll
        for (int ni = 0; ni < AN; ++ni) {
            const int n  = n0 + wn + ni*16 + fr;
            const int mb = m0 + wm + mi*16 + (lane >> 4) * 4;
            f32x4 v = acc[mi][ni];
            ushort4 o;
#pragma unroll
            for (int q = 0; q < 4; ++q) {
                float yv = v[q] + bias[(size_t)b*M + mb + q];
                yv = 1.0f / (1.0f + __expf(-yv));
                ((unsigned short*)&o)[q] = f2bf(yv);
            }
            *(ushort4*)&Yt[((size_t)b*NSP + n)*M + mb] = o;
        }
    }
}

// Layer 5: out[b][n] = sum_k act4T[b][n][k] * w5[b][k] + b5[b]   (no sigmoid)
__global__ void fc_final(const unsigned short* __restrict__ A4,
                         const float* __restrict__ W5,
                         const float* __restrict__ B5,
                         float* __restrict__ out)
{
    const int b = blockIdx.x;
    const int t = threadIdx.x;  // 0..255 spatial
    const unsigned short* row = A4 + ((size_t)b * NSP + t) * 128;
    const float* w = W5 + (size_t)b * 128;
    float acc = B5[b];
#pragma unroll
    for (int k = 0; k < 128; k += 8) {
        uint4 v = *(const uint4*)(row + k);
        acc += bf2f((unsigned short)(v.x & 0xffff)) * w[k+0];
        acc += bf2f((unsigned short)(v.x >> 16))    * w[k+1];
        acc += bf2f((unsigned short)(v.y & 0xffff)) * w[k+2];
        acc += bf2f((unsigned short)(v.y >> 16))    * w[k+3];
        acc += bf2f((unsigned short)(v.z & 0xffff)) * w[k+4];
        acc += bf2f((unsigned short)(v.z >> 16))    * w[k+5];
        acc += bf2f((unsigned short)(v.w & 0xffff)) * w[k+6];
        acc += bf2f((unsigned short)(v.w >> 16))    * w[k+7];
    }
    out[b * NSP + t] = acc;
}

extern "C" void kernel_launch(void* const* d_in, const int* in_sizes, int n_in,
                              void* d_out, int out_size, void* d_ws, size_t ws_size,
                              hipStream_t stream)
{
    const float* x  = (const float*)d_in[0];
    const float* w1 = (const float*)d_in[1];
    const float* b1 = (const float*)d_in[2];
    const float* w2 = (const float*)d_in[3];
    const float* b2 = (const float*)d_in[4];
    const float* w3 = (const float*)d_in[5];
    const float* b3 = (const float*)d_in[6];
    const float* w4 = (const float*)d_in[7];
    const float* b4 = (const float*)d_in[8];
    const float* w5 = (const float*)d_in[9];
    const float* b5 = (const float*)d_in[10];

    unsigned short* ws0 = (unsigned short*)d_ws;
    const dim3 blk(256);

    const size_t XT_U16   = (size_t)64 * 256 * 2048;   // 33.55M u16 = 67.1 MB
    const size_t ACT1_U16 = (size_t)64 * 256 * 1024;   // 33.55 MB
    const size_t need = (XT_U16 + ACT1_U16) * 2;       // 100.7 MB

    if (ws_size >= need) {
        // xT @ [0, XT); act1 @ [XT, XT+ACT1); act2/act3/act4 reuse xT region (xT dead after L1).
        unsigned short* xT   = ws0;
        unsigned short* act1 = ws0 + XT_U16;
        unsigned short* act2 = ws0;                                    // 16.78M u16
        unsigned short* act3 = ws0 + (size_t)64 * 256 * 512;           // after act2
        unsigned short* act4 = ws0 + (size_t)64 * 256 * (512 + 256);   // after act3

        xpose<<<dim3(128, 64), blk, 0, stream>>>(x, xT);
        fc_gemm<128, false><<<dim3(8, 128), blk, 0, stream>>>(w1, b1, xT,   act1, 1024, 2048);
        fc_gemm<128, false><<<dim3(4, 128), blk, 0, stream>>>(w2, b2, act1, act2,  512, 1024);
        fc_gemm< 64, false><<<dim3(4, 128), blk, 0, stream>>>(w3, b3, act2, act3,  256,  512);
        fc_gemm< 64, false><<<dim3(2, 128), blk, 0, stream>>>(w4, b4, act3, act4,  128,  256);
        fc_final<<<dim3(64), blk, 0, stream>>>(act4, w5, b5, (float*)d_out);
    } else {
        // Fallback: fused-transpose layer 1 (50.3 MB ws), previous-round layout.
        unsigned short* act1 = ws0;
        unsigned short* act2 = ws0 + ACT1_U16;
        unsigned short* act3 = ws0;
        unsigned short* act4 = ws0 + ACT1_U16;

        fc_gemm<128, true ><<<dim3(8, 128), blk, 0, stream>>>(w1, b1, x,    act1, 1024, 2048);
        fc_gemm<128, false><<<dim3(4, 128), blk, 0, stream>>>(w2, b2, act1, act2,  512, 1024);
        fc_gemm< 64, false><<<dim3(4, 128), blk, 0, stream>>>(w3, b3, act2, act3,  256,  512);
        fc_gemm< 64, false><<<dim3(2, 128), blk, 0, stream>>>(w4, b4, act3, act4,  128,  256);
        fc_final<<<dim3(64), blk, 0, stream>>>(act4, w5, b5, (float*)d_out);
    }
}

// Round 3
// 376.845 us; speedup vs baseline: 1.3850x; 1.3850x over previous
//
#include <hip/hip_runtime.h>
#include <hip/hip_bf16.h>
#include <cstdint>

#define DEVINL __device__ __forceinline__

typedef __attribute__((ext_vector_type(8))) short bf16x8;
typedef __attribute__((ext_vector_type(4))) float f32x4;

DEVINL unsigned short f2bf(float f) {
    union { float f; unsigned u; } v; v.f = f;
    unsigned r = v.u + 0x7fffu + ((v.u >> 16) & 1u);   // RNE
    return (unsigned short)(r >> 16);
}
DEVINL float bf2f(unsigned short h) {
    union { unsigned u; float f; } v; v.u = ((unsigned)h) << 16;
    return v.f;
}

constexpr int BN = 256, BK = 32;
constexpr int PITCH = 40;   // u16/row = 80B: ds_read_b128 by consecutive-8-lane groups covers all 32 banks once
constexpr int NSP = 256;    // H*W

// ---------------------------------------------------------------------------
// Transpose + bf16 convert: x[b][2048][256] f32 -> xT[b][256][2048] bf16.
// Padded 64x65 f32 LDS tile; both phases exactly 2 lanes/bank (free).
__global__ __launch_bounds__(256)
void xpose(const float* __restrict__ x, unsigned short* __restrict__ xT)
{
    __shared__ float sh[64][65];
    const int b   = blockIdx.y;
    const int kt  = blockIdx.x & 31;     // 2048/64
    const int ntb = blockIdx.x >> 5;     // 256/64
    const int k0 = kt * 64, n0 = ntb * 64;

    const int r = threadIdx.x >> 4;          // 0..15
    const int c = (threadIdx.x & 15) * 4;    // 0..60

    const float* xb = x + ((size_t)b * 2048 + k0) * 256 + n0;
#pragma unroll
    for (int i = 0; i < 4; ++i) {
        float4 v = *(const float4*)(xb + (size_t)(r + 16 * i) * 256 + c);
        sh[r + 16 * i][c + 0] = v.x;
        sh[r + 16 * i][c + 1] = v.y;
        sh[r + 16 * i][c + 2] = v.z;
        sh[r + 16 * i][c + 3] = v.w;
    }
    __syncthreads();
#pragma unroll
    for (int i = 0; i < 4; ++i) {
        const int rr = r + 16 * i;           // n within tile
        ushort4 o;
        o.x = f2bf(sh[c + 0][rr]);
        o.y = f2bf(sh[c + 1][rr]);
        o.z = f2bf(sh[c + 2][rr]);
        o.w = f2bf(sh[c + 3][rr]);
        *(ushort4*)(xT + ((size_t)b * NSP + n0 + rr) * 2048 + k0 + c) = o;
    }
}

// ---------------------------------------------------------------------------
// Y^T[b][n][m] = sigmoid?( sum_k W[b][m][k]*XT[b][n][k] + bias[b][m] ), bf16 out.
// Full-N blocks (BN=256): each W panel is fetched from HBM exactly once.
// 512 threads = 8 waves arranged WM x WN over the BM x 256 tile (64-wide wave tiles).
template<int BM, int WM, int WN>
__global__ __launch_bounds__(512, 2)
void fc_gemm(const float* __restrict__ Wt, const float* __restrict__ bias,
             const unsigned short* __restrict__ X, unsigned short* __restrict__ Yt,
             int M, int K)
{
    constexpr int TM = BM / WM;     // 64
    constexpr int TN = BN / WN;     // 64 or 32
    constexpr int AM = TM / 16;     // 4
    constexpr int AN = TN / 16;     // 4 or 2
    constexpr int AI = BM / 64;     // A-staging float4s per thread (2 or 1)

    const int b  = blockIdx.y;
    const int m0 = blockIdx.x * BM;

    __shared__ __align__(16) unsigned short sA[2][BM * PITCH];
    __shared__ __align__(16) unsigned short sB[2][BN * PITCH];

    const int tid  = threadIdx.x;
    const int lane = tid & 63;
    const int wid  = tid >> 6;
    const int wm   = (wid / WN) * TM;
    const int wn   = (wid % WN) * TN;
    const int fr   = lane & 15;
    const int fo   = (lane >> 4) * 8;

    // A staging: BM x 32 fp32 -> bf16.  BM=128: thread owns (m=tid>>2, c=(tid&3)*4 and +16).
    //                                   BM=64 : thread owns (m=tid>>3, c=(tid&7)*4).
    const int am = (AI == 2) ? (tid >> 2) : (tid >> 3);
    const int ac = (AI == 2) ? (tid & 3) * 4 : (tid & 7) * 4;
    const float* Wb = Wt + (size_t)b * M * K + (size_t)m0 * K;

    // B staging: 256 x 32 bf16: thread owns row n=tid>>1, two uint4 at (tid&1)*16 and +8.
    const int bn = tid >> 1;
    const int bc = (tid & 1) * 16;
    const unsigned short* Xb = X + (size_t)b * NSP * K;

    float4 aR[AI];
    uint4  bR[2];

    auto loadA = [&](int k0) {
#pragma unroll
        for (int i = 0; i < AI; ++i)
            aR[i] = *(const float4*)(Wb + (size_t)am * K + k0 + ac + i * 16);
    };
    auto loadB = [&](int k0) {
#pragma unroll
        for (int i = 0; i < 2; ++i)
            bR[i] = *(const uint4*)(Xb + (size_t)bn * K + k0 + bc + i * 8);
    };
    auto storeA = [&](int buf) {
#pragma unroll
        for (int i = 0; i < AI; ++i) {
            ushort4 p;
            p.x = f2bf(aR[i].x); p.y = f2bf(aR[i].y);
            p.z = f2bf(aR[i].z); p.w = f2bf(aR[i].w);
            *(ushort4*)&sA[buf][am * PITCH + ac + i * 16] = p;
        }
    };
    auto storeB = [&](int buf) {
#pragma unroll
        for (int i = 0; i < 2; ++i)
            *(uint4*)&sB[buf][bn * PITCH + bc + i * 8] = bR[i];
    };

    f32x4 acc[AM][AN] = {};

    loadA(0); loadB(0);
    storeA(0); storeB(0);
    __syncthreads();

    const int NT = K / BK;
    int cur = 0;
#pragma unroll 1
    for (int t = 0; t < NT; ++t) {
        if (t + 1 < NT) { loadA((t + 1) * BK); loadB((t + 1) * BK); }  // in flight under MFMA

        bf16x8 af[AM], bfr[AN];
#pragma unroll
        for (int i = 0; i < AM; ++i)
            af[i] = *(const bf16x8*)&sA[cur][(wm + i * 16 + fr) * PITCH + fo];
#pragma unroll
        for (int i = 0; i < AN; ++i)
            bfr[i] = *(const bf16x8*)&sB[cur][(wn + i * 16 + fr) * PITCH + fo];
#pragma unroll
        for (int mi = 0; mi < AM; ++mi)
#pragma unroll
            for (int ni = 0; ni < AN; ++ni)
                acc[mi][ni] = __builtin_amdgcn_mfma_f32_16x16x32_bf16(af[mi], bfr[ni], acc[mi][ni], 0, 0, 0);

        if (t + 1 < NT) { storeA(cur ^ 1); storeB(cur ^ 1); }
        __syncthreads();
        cur ^= 1;
    }

    // Epilogue: D col = lane&15 (n), rows = (lane>>4)*4+q (m). Store Y^T[b][n][m] bf16.
    const bool SIG = (M != 1);  // always true here; final layer handled elsewhere
    (void)SIG;
#pragma unroll
    for (int mi = 0; mi < AM; ++mi) {
#pragma unroll
        for (int ni = 0; ni < AN; ++ni) {
            const int n  = wn + ni * 16 + fr;
            const int mb = m0 + wm + mi * 16 + (lane >> 4) * 4;
            f32x4 v = acc[mi][ni];
            ushort4 o;
#pragma unroll
            for (int q = 0; q < 4; ++q) {
                float yv = v[q] + bias[(size_t)b * M + mb + q];
                yv = 1.0f / (1.0f + __expf(-yv));
                ((unsigned short*)&o)[q] = f2bf(yv);
            }
            *(ushort4*)&Yt[((size_t)b * NSP + n) * M + mb] = o;
        }
    }
}

// Layer 5: out[b][n] = sum_k act4T[b][n][k] * w5[b][k] + b5[b]   (no sigmoid)
__global__ void fc_final(const unsigned short* __restrict__ A4,
                         const float* __restrict__ W5,
                         const float* __restrict__ B5,
                         float* __restrict__ out)
{
    const int b = blockIdx.x;
    const int t = threadIdx.x;  // 0..255 spatial
    const unsigned short* row = A4 + ((size_t)b * NSP + t) * 128;
    const float* w = W5 + (size_t)b * 128;
    float acc = B5[b];
#pragma unroll
    for (int k = 0; k < 128; k += 8) {
        uint4 v = *(const uint4*)(row + k);
        acc += bf2f((unsigned short)(v.x & 0xffff)) * w[k+0];
        acc += bf2f((unsigned short)(v.x >> 16))    * w[k+1];
        acc += bf2f((unsigned short)(v.y & 0xffff)) * w[k+2];
        acc += bf2f((unsigned short)(v.y >> 16))    * w[k+3];
        acc += bf2f((unsigned short)(v.z & 0xffff)) * w[k+4];
        acc += bf2f((unsigned short)(v.z >> 16))    * w[k+5];
        acc += bf2f((unsigned short)(v.w & 0xffff)) * w[k+6];
        acc += bf2f((unsigned short)(v.w >> 16))    * w[k+7];
    }
    out[b * NSP + t] = acc;
}

extern "C" void kernel_launch(void* const* d_in, const int* in_sizes, int n_in,
                              void* d_out, int out_size, void* d_ws, size_t ws_size,
                              hipStream_t stream)
{
    const float* x  = (const float*)d_in[0];
    const float* w1 = (const float*)d_in[1];
    const float* b1 = (const float*)d_in[2];
    const float* w2 = (const float*)d_in[3];
    const float* b2 = (const float*)d_in[4];
    const float* w3 = (const float*)d_in[5];
    const float* b3 = (const float*)d_in[6];
    const float* w4 = (const float*)d_in[7];
    const float* b4 = (const float*)d_in[8];
    const float* w5 = (const float*)d_in[9];
    const float* b5 = (const float*)d_in[10];

    unsigned short* ws0 = (unsigned short*)d_ws;

    // u16-element offsets. xT dead after L1 -> act2/3/4 reuse its region.
    const size_t XT   = (size_t)64 * 256 * 2048;  // 33,554,432 u16 (67.1 MB)
    unsigned short* xT   = ws0;
    unsigned short* act1 = ws0 + XT;                          // 16.78M u16
    unsigned short* act2 = ws0;                               //  8.39M u16
    unsigned short* act3 = ws0 + (size_t)64 * 256 * 512;      //  4.19M u16
    unsigned short* act4 = ws0 + (size_t)64 * 256 * (512+256);//  2.10M u16

    xpose<<<dim3(128, 64), dim3(256), 0, stream>>>(x, xT);
    fc_gemm<128, 2, 4><<<dim3(8, 64), dim3(512), 0, stream>>>(w1, b1, xT,   act1, 1024, 2048);
    fc_gemm<128, 2, 4><<<dim3(4, 64), dim3(512), 0, stream>>>(w2, b2, act1, act2,  512, 1024);
    fc_gemm< 64, 1, 8><<<dim3(4, 64), dim3(512), 0, stream>>>(w3, b3, act2, act3,  256,  512);
    fc_gemm< 64, 1, 8><<<dim3(2, 64), dim3(512), 0, stream>>>(w4, b4, act3, act4,  128,  256);
    fc_final<<<dim3(64), dim3(256), 0, stream>>>(act4, w5, b5, (float*)d_out);
}